// Round 1
// baseline (519.987 us; speedup 1.0000x reference)
//
#include <hip/hip_runtime.h>
#include <math.h>

constexpr int B = 16, N = 200, D = 128, H = 8;
constexpr int JT = 40;                     // j-tile for dis staging
constexpr float NEG_SLOPE = 0.2f;

// ---------------------------------------------------------------------------
// Kernel A: fold a3 into W_e:  v[h][d] = sum_n W_e[d][h*16+n] * a[32+n]
// ---------------------------------------------------------------------------
__global__ void prep_v(const float* __restrict__ We, const float* __restrict__ a,
                       float* __restrict__ v) {
    int d = threadIdx.x;                   // 128 threads
    float a3[16];
#pragma unroll
    for (int nn = 0; nn < 16; ++nn) a3[nn] = a[32 + nn];
    for (int h = 0; h < H; ++h) {
        float s = 0.f;
#pragma unroll
        for (int nn = 0; nn < 16; ++nn) s = fmaf(We[d * D + h * 16 + nn], a3[nn], s);
        v[h * D + d] = s;                  // [H][D] layout
    }
}

// ---------------------------------------------------------------------------
// Kernel B: g = h @ W (row per block), plus s_i = g.a1, s_j = g.a2 per (row,h)
// ---------------------------------------------------------------------------
__global__ void prep_g(const float* __restrict__ hmat, const float* __restrict__ W,
                       const float* __restrict__ a,
                       float* __restrict__ g, float* __restrict__ s_i,
                       float* __restrict__ s_j) {
    const int row = blockIdx.x;            // b*N + i
    const int t = threadIdx.x;             // 128 threads
    __shared__ __align__(16) float hrow[D];
    __shared__ float p1[D], p2[D];
    if (t < 32) ((float4*)hrow)[t] = ((const float4*)(hmat + (size_t)row * D))[t];
    __syncthreads();
    float acc = 0.f;
#pragma unroll 4
    for (int d = 0; d < D; ++d) acc = fmaf(hrow[d], W[d * D + t], acc);
    g[(size_t)row * D + t] = acc;
    p1[t] = acc * a[t & 15];
    p2[t] = acc * a[16 + (t & 15)];
    __syncthreads();
    if (t < H) {
        float s1 = 0.f, s2 = 0.f;
#pragma unroll
        for (int nn = 0; nn < 16; ++nn) { s1 += p1[t * 16 + nn]; s2 += p2[t * 16 + nn]; }
        s_i[row * H + t] = s1;
        s_j[row * H + t] = s2;
    }
}

// ---------------------------------------------------------------------------
// Kernel C: fused s_e + leaky_relu + mask + softmax(j) + PV, one block per (b,i)
// 320 threads = 5 waves.
// ---------------------------------------------------------------------------
__global__ void __launch_bounds__(320)
attn_fused(const float* __restrict__ dis, const int* __restrict__ adj,
           const float* __restrict__ g, const float* __restrict__ s_i,
           const float* __restrict__ s_j, const float* __restrict__ v,
           float* __restrict__ out) {
    const int bi = blockIdx.x;             // b*N + i
    const int b  = bi / N;
    const int t  = threadIdx.x;

    __shared__ __align__(16) float ds_tile[JT][132];   // padded: conflict-free
    __shared__ __align__(16) float se[N][H];           // s_e -> e -> p
    __shared__ __align__(16) float sjs[N][H];
    __shared__ __align__(16) float vv[H][132];
    __shared__ int   adjs[N];
    __shared__ float red[256];
    __shared__ float sis[H], maxh[H], invh[H];

    // ---- preload per-block data --------------------------------------------
    if (t < 256) {                         // v: 1024 floats = 256 float4
        float4 x = ((const float4*)v)[t];
        int hh = t >> 5, dd = (t & 31) * 4;
        vv[hh][dd] = x.x; vv[hh][dd + 1] = x.y; vv[hh][dd + 2] = x.z; vv[hh][dd + 3] = x.w;
    }
    {                                      // s_j[b,:,:]: 1600 floats = 400 float4
        const float4* sj4 = (const float4*)(s_j + (size_t)b * N * H);
        float4* dst = (float4*)&sjs[0][0];
        for (int f = t; f < 400; f += 320) dst[f] = sj4[f];
    }
    if (t < N) adjs[t] = adj[(size_t)bi * N + t];
    if (t < H) sis[t] = s_i[(size_t)bi * H + t];
    __syncthreads();

    // ---- s_e: dot(dis_row, v[:,h]) over 5 tiles of 40 rows -----------------
    for (int tile = 0; tile < N / JT; ++tile) {
        const int j0 = tile * JT;
        const float4* src = (const float4*)(dis + ((size_t)bi * N + j0) * D);
        for (int f = t; f < JT * D / 4; f += 320) {    // 1280 float4, coalesced
            float4 x = src[f];
            int r = f >> 5, c = (f & 31) * 4;
            *(float4*)&ds_tile[r][c] = x;
        }
        __syncthreads();
        {                                   // one (j,h) pair per thread
            const int j = t >> 3, h = t & 7;
            float s = 0.f;
#pragma unroll
            for (int d = 0; d < D; d += 4) {
                float4 x = *(const float4*)&ds_tile[j][d];
                float4 w = *(const float4*)&vv[h][d];
                s = fmaf(x.x, w.x, s); s = fmaf(x.y, w.y, s);
                s = fmaf(x.z, w.z, s); s = fmaf(x.w, w.w, s);
            }
            se[j0 + j][h] = s;
        }
        __syncthreads();
    }

    // ---- e = leaky_relu(s_i + s_j + s_e), mask -----------------------------
    for (int idx = t; idx < N * H; idx += 320) {
        int j = idx >> 3, h = idx & 7;
        float val = sis[h] + sjs[j][h] + se[j][h];
        val = val > 0.f ? val : NEG_SLOPE * val;
        se[j][h] = (adjs[j] != 0) ? val : -__builtin_inff();
    }
    __syncthreads();

    // ---- softmax over j, per h (8-lane h-groups, shfl_xor reduce) ----------
    {
        const int h = t & 7, jr = t >> 3;   // jr in 0..39, 5 j's each
        float m = -__builtin_inff();
        for (int j = jr; j < N; j += 40) m = fmaxf(m, se[j][h]);
        m = fmaxf(m, __shfl_xor(m, 8));
        m = fmaxf(m, __shfl_xor(m, 16));
        m = fmaxf(m, __shfl_xor(m, 32));
        if ((t & 63) < 8) red[(t >> 6) * 8 + h] = m;
    }
    __syncthreads();
    if (t < 8) {
        float m = red[t];
        for (int w = 1; w < 5; ++w) m = fmaxf(m, red[w * 8 + t]);
        maxh[t] = m;
    }
    __syncthreads();
    {
        const int h = t & 7, jr = t >> 3;
        const float mh = maxh[h];
        float s = 0.f;
        for (int j = jr; j < N; j += 40) {
            float x = se[j][h];
            float p = (x == -__builtin_inff()) ? 0.f : __expf(x - mh);
            se[j][h] = p;
            s += p;
        }
        s += __shfl_xor(s, 8);
        s += __shfl_xor(s, 16);
        s += __shfl_xor(s, 32);
        if ((t & 63) < 8) red[(t >> 6) * 8 + h] = s;
    }
    __syncthreads();
    if (t < 8) {
        float s = red[t];
        for (int w = 1; w < 5; ++w) s += red[w * 8 + t];
        invh[t] = (s > 0.f) ? 1.f / s : 0.f;
    }
    __syncthreads();

    // ---- PV: out[bi, h*16+f] = inv[h] * sum_j p[j][h] * g[b,j,h*16+f] ------
    if (t < 256) {
        const int hf = t & 127, jpar = t >> 7;     // split j over 2 half-grids
        const float* gb = g + (size_t)b * N * D + hf;
        float acc = 0.f;
#pragma unroll 4
        for (int j = jpar; j < N; j += 2)
            acc = fmaf(se[j][hf >> 4], gb[(size_t)j * D], acc);
        red[t] = acc;
    }
    __syncthreads();
    if (t < 128)
        out[(size_t)bi * D + t] = (red[t] + red[t + 128]) * invh[t >> 4];
}

// ---------------------------------------------------------------------------
extern "C" void kernel_launch(void* const* d_in, const int* in_sizes, int n_in,
                              void* d_out, int out_size, void* d_ws, size_t ws_size,
                              hipStream_t stream) {
    const float* hmat = (const float*)d_in[0];
    const int*   adj  = (const int*)d_in[1];
    const float* dis  = (const float*)d_in[2];
    const float* W    = (const float*)d_in[3];
    const float* We   = (const float*)d_in[4];
    const float* a    = (const float*)d_in[5];
    float* out = (float*)d_out;

    float* ws  = (float*)d_ws;
    float* v   = ws;                       // 1024
    float* g   = ws + 1024;                // 409600
    float* s_i = g + (size_t)B * N * D;    // 25600
    float* s_j = s_i + (size_t)B * N * H;  // 25600

    prep_v<<<1, 128, 0, stream>>>(We, a, v);
    prep_g<<<B * N, 128, 0, stream>>>(hmat, W, a, g, s_i, s_j);
    attn_fused<<<B * N, 320, 0, stream>>>(dis, adj, g, s_i, s_j, v, out);
}

// Round 2
// 482.937 us; speedup vs baseline: 1.0767x; 1.0767x over previous
//
#include <hip/hip_runtime.h>
#include <math.h>

constexpr int B = 16, N = 200, D = 128, H = 8;
constexpr float NEG_SLOPE = 0.2f;

// DPP-based add of lane (l + n) % 16 within each 16-lane row: pure VALU reduce.
template<int CTRL>
__device__ __forceinline__ float dpp_add(float x) {
    union { float f; int i; } u, r;
    u.f = x;
    r.i = __builtin_amdgcn_update_dpp(0, u.i, CTRL, 0xf, 0xf, true);
    return x + r.f;
}

// ---------------------------------------------------------------------------
// prep: blocks 0..B*N-1: g = h@W row, s_i, s_j.  Block B*N: fold a3 into W_e.
// ---------------------------------------------------------------------------
__global__ void prep_all(const float* __restrict__ hmat, const float* __restrict__ W,
                         const float* __restrict__ We, const float* __restrict__ a,
                         float* __restrict__ g, float* __restrict__ s_i,
                         float* __restrict__ s_j, float* __restrict__ v) {
    const int row = blockIdx.x;
    const int t = threadIdx.x;             // 128 threads

    if (row == B * N) {                    // v[h][d] = sum_n We[d][h*16+n]*a[32+n]
        float a3[16];
#pragma unroll
        for (int nn = 0; nn < 16; ++nn) a3[nn] = a[32 + nn];
        for (int h = 0; h < H; ++h) {
            float s = 0.f;
#pragma unroll
            for (int nn = 0; nn < 16; ++nn) s = fmaf(We[t * D + h * 16 + nn], a3[nn], s);
            v[h * D + t] = s;              // [H][D]
        }
        return;
    }

    __shared__ __align__(16) float hrow[D];
    __shared__ float p1[D], p2[D];
    if (t < 32) ((float4*)hrow)[t] = ((const float4*)(hmat + (size_t)row * D))[t];
    __syncthreads();
    float c0 = 0.f, c1 = 0.f, c2 = 0.f, c3 = 0.f;
#pragma unroll 8
    for (int d = 0; d < D; d += 4) {
        c0 = fmaf(hrow[d],     W[(d)     * D + t], c0);
        c1 = fmaf(hrow[d + 1], W[(d + 1) * D + t], c1);
        c2 = fmaf(hrow[d + 2], W[(d + 2) * D + t], c2);
        c3 = fmaf(hrow[d + 3], W[(d + 3) * D + t], c3);
    }
    float acc = (c0 + c1) + (c2 + c3);
    g[(size_t)row * D + t] = acc;
    p1[t] = acc * a[t & 15];
    p2[t] = acc * a[16 + (t & 15)];
    __syncthreads();
    if (t < H) {
        float s1 = 0.f, s2 = 0.f;
#pragma unroll
        for (int nn = 0; nn < 16; ++nn) { s1 += p1[t * 16 + nn]; s2 += p2[t * 16 + nn]; }
        s_i[row * H + t] = s1;
        s_j[row * H + t] = s2;
    }
}

// ---------------------------------------------------------------------------
// fused: stream dis global->regs, DPP row-reduce -> s_e; e+mask+softmax; PV.
// 320 threads = 5 waves. Wave w owns rows [40w, 40w+40), 4 rows / iteration.
// ---------------------------------------------------------------------------
__global__ void __launch_bounds__(320, 4)
attn_fused(const float* __restrict__ dis, const int* __restrict__ adj,
           const float* __restrict__ g, const float* __restrict__ s_i,
           const float* __restrict__ s_j, const float* __restrict__ v,
           float* __restrict__ out) {
    const int bi = blockIdx.x;             // b*N + i
    const int b  = bi / N;
    const int t  = threadIdx.x;
    const int wave = t >> 6;               // 0..4
    const int lane = t & 63;
    const int grp  = lane >> 4;            // row-in-iter 0..3
    const int c    = lane & 15;            // d-chunk 0..15

    __shared__ __align__(16) float se[N][H];    // s_e -> e -> p
    __shared__ __align__(16) float sjs[N][H];
    __shared__ int   adjs[N];
    __shared__ float red[256];
    __shared__ float sis[H], maxh[H], invh[H];

    // ---- v into registers: lane covers d in [4c,4c+4) U [64+4c,64+4c+4) ----
    float4 va[H], vb[H];
#pragma unroll
    for (int h = 0; h < H; ++h) {
        va[h] = *(const float4*)(v + h * D + 4 * c);
        vb[h] = *(const float4*)(v + h * D + 64 + 4 * c);
    }

    // ---- small preloads (overlap with dis streaming below) -----------------
    {
        const float4* sj4 = (const float4*)(s_j + (size_t)b * N * H);
        float4* dst = (float4*)&sjs[0][0];
        for (int f = t; f < N * H / 4; f += 320) dst[f] = sj4[f];
    }
    if (t < N) adjs[t] = adj[(size_t)bi * N + t];
    if (t < H) sis[t] = s_i[(size_t)bi * H + t];

    // ---- s_e stream: no LDS for dis, software prefetch 1 iter --------------
    const float* dbase = dis + ((size_t)bi * N + wave * 40 + grp) * D + 4 * c;
    float4 cA = *(const float4*)(dbase);
    float4 cB = *(const float4*)(dbase + 64);
#pragma unroll 2
    for (int it = 0; it < 10; ++it) {
        float4 nA, nB;
        if (it < 9) {
            nA = *(const float4*)(dbase + (it + 1) * 4 * D);
            nB = *(const float4*)(dbase + (it + 1) * 4 * D + 64);
        }
        float acc[H];
#pragma unroll
        for (int h = 0; h < H; ++h) {
            acc[h] = fmaf(cA.x, va[h].x, fmaf(cA.y, va[h].y,
                     fmaf(cA.z, va[h].z, fmaf(cA.w, va[h].w,
                     fmaf(cB.x, vb[h].x, fmaf(cB.y, vb[h].y,
                     fmaf(cB.z, vb[h].z, cB.w * vb[h].w)))))));
        }
#pragma unroll
        for (int h = 0; h < H; ++h) {      // sum over the 16 lanes of this row
            float x = acc[h];
            x = dpp_add<0x121>(x);         // row_ror:1
            x = dpp_add<0x122>(x);         // row_ror:2
            x = dpp_add<0x124>(x);         // row_ror:4
            x = dpp_add<0x128>(x);         // row_ror:8
            acc[h] = x;
        }
        if (c == 0) {
            const int row = wave * 40 + it * 4 + grp;
            *(float4*)&se[row][0] = float4{acc[0], acc[1], acc[2], acc[3]};
            *(float4*)&se[row][4] = float4{acc[4], acc[5], acc[6], acc[7]};
        }
        cA = nA; cB = nB;
    }
    __syncthreads();

    // ---- e = leaky_relu(s_i+s_j+s_e), mask, fused running max --------------
    const int h8 = t & 7, jr = t >> 3;     // jr 0..39
    {
        const float si = sis[h8];
        float m = -__builtin_inff();
#pragma unroll
        for (int k = 0; k < 5; ++k) {
            const int j = jr + 40 * k;
            float val = si + sjs[j][h8] + se[j][h8];
            val = val > 0.f ? val : NEG_SLOPE * val;
            val = adjs[j] ? val : -__builtin_inff();
            se[j][h8] = val;
            m = fmaxf(m, val);
        }
        m = fmaxf(m, __shfl_xor(m, 8));
        m = fmaxf(m, __shfl_xor(m, 16));
        m = fmaxf(m, __shfl_xor(m, 32));
        if (lane < 8) red[wave * 8 + h8] = m;
    }
    __syncthreads();
    if (t < 8) {
        float m = red[t];
        for (int w = 1; w < 5; ++w) m = fmaxf(m, red[w * 8 + t]);
        maxh[t] = m;
    }
    __syncthreads();
    {
        const float mh = maxh[h8];
        float s = 0.f;
#pragma unroll
        for (int k = 0; k < 5; ++k) {
            const int j = jr + 40 * k;
            const float x = se[j][h8];
            const float p = (x == -__builtin_inff()) ? 0.f : __expf(x - mh);
            se[j][h8] = p;
            s += p;
        }
        s += __shfl_xor(s, 8);
        s += __shfl_xor(s, 16);
        s += __shfl_xor(s, 32);
        if (lane < 8) red[wave * 8 + h8] = s;
    }
    __syncthreads();
    if (t < 8) {
        float s = red[t];
        for (int w = 1; w < 5; ++w) s += red[w * 8 + t];
        invh[t] = (s > 0.f) ? 1.f / s : 0.f;
    }
    __syncthreads();

    // ---- PV: out[bi, hf] = inv[h] * sum_j p[j][h] * g[b,j,hf] --------------
    if (t < 256) {
        const int hf = t & 127, jpar = t >> 7;
        const float* gb = g + (size_t)b * N * D + hf;
        float acc = 0.f;
#pragma unroll 4
        for (int j = jpar; j < N; j += 2)
            acc = fmaf(se[j][hf >> 4], gb[(size_t)j * D], acc);
        red[t] = acc;
    }
    __syncthreads();
    if (t < 128)
        out[(size_t)bi * D + t] = (red[t] + red[t + 128]) * invh[t >> 4];
}

// ---------------------------------------------------------------------------
extern "C" void kernel_launch(void* const* d_in, const int* in_sizes, int n_in,
                              void* d_out, int out_size, void* d_ws, size_t ws_size,
                              hipStream_t stream) {
    const float* hmat = (const float*)d_in[0];
    const int*   adj  = (const int*)d_in[1];
    const float* dis  = (const float*)d_in[2];
    const float* W    = (const float*)d_in[3];
    const float* We   = (const float*)d_in[4];
    const float* a    = (const float*)d_in[5];
    float* out = (float*)d_out;

    float* ws  = (float*)d_ws;
    float* v   = ws;                       // 1024
    float* g   = ws + 1024;                // B*N*D
    float* s_i = g + (size_t)B * N * D;    // B*N*H
    float* s_j = s_i + (size_t)B * N * H;  // B*N*H

    prep_all<<<B * N + 1, 128, 0, stream>>>(hmat, W, We, a, g, s_i, s_j, v);
    attn_fused<<<B * N, 320, 0, stream>>>(dis, adj, g, s_i, s_j, v, out);
}